// Round 9
// baseline (367.716 us; speedup 1.0000x reference)
//
#include <hip/hip_runtime.h>
#include <hip/hip_fp16.h>

// ---------------------------------------------------------------------------
// ContrastiveGNN: 2-layer GCN + global mean pool + linear head.
//
//   hs1[v]   = (x[v] @ W1) * dinv[v]            (MFMA f16 GEMM, f32 acc, f16 out)
//   g1[v]    = relu(dinv[v]*(hs1[v] + sum_{u->v} hs1[u]) + b1)
//   gs1[v]   = g1[v] * dinv[v]                  (gather1, f32 math, f16 store)
//   a2[v]    = dinv[v]*(gs1[v] + sum_{u->v} gs1[u])
//   pool[g]  = mean_{v in g} a2[v]              (gather2, LDS-pooled atomics)
//   emb      = pool @ W2 + b2 ; logits = emb @ Wg + bg   (tiny head)
//
// CSR build: K1 chunk-bucket-sorts edges into block-private regions (r8,
// verified).  r8's monolithic K3 (391 blocks, 14% occupancy, 117us) is split
// into K3a/K3b/K3c at (B,8) parallelism; all writes stay bucket-private.
// r9: gather2's 12.8M global f32 pool atomics (= 100MB of HBM RMW writes!)
// are batched through LDS: one 128-atomic flush per block.
//
// Gathers (VERIFIED r4/r5/r7): 1 wave/node, lane holds features
// [2*lane, 2*lane+1] (half2), software-pipelined 8-deep.
// DO NOT reintroduce the half-wave + __shfl restructure (rounds 2/3).
// DO NOT trade wave count for per-wave MLP (r6: conserved concurrency).
// ---------------------------------------------------------------------------

#define TPB 256
#define CHUNK 4096          // edges per K1 block
#define MAXB 512            // max buckets AND max chunks
#define SUBS 8              // sub-blocks per bucket in K3a/K3c

typedef _Float16 half8 __attribute__((ext_vector_type(8)));
typedef float floatx4 __attribute__((ext_vector_type(4)));

// exclusive scan of a[0..512) in LDS, 256 threads; part[255] = total.
__device__ __forceinline__ void exscan512(int* a, int* part, int t) {
    int x0 = a[2 * t], x1 = a[2 * t + 1];
    part[t] = x0 + x1;
    __syncthreads();
    for (int off = 1; off < 256; off <<= 1) {
        int v = (t >= off) ? part[t - off] : 0;
        __syncthreads();
        part[t] += v;
        __syncthreads();
    }
    int base = (t > 0) ? part[t - 1] : 0;
    a[2 * t] = base;
    a[2 * t + 1] = base + x0;
    __syncthreads();
}

// ---- K1: per-chunk bucket sort of edges (bucket = dst>>8) ----
__global__ __launch_bounds__(256) void k1_bucket(const int* __restrict__ ei, int E,
                                                 int B, int nchunks,
                                                 uint2* __restrict__ sorted,
                                                 int* __restrict__ histT,
                                                 int* __restrict__ sstartT,
                                                 int* __restrict__ bucketTot) {
    __shared__ int hcnt[MAXB], hoff[MAXB], hcur[MAXB], part[256];
    int c = blockIdx.x, t = threadIdx.x;
    int e0 = c * CHUNK;
    int m = E - e0; if (m > CHUNK) m = CHUNK;
    for (int i = t; i < MAXB; i += 256) { hcnt[i] = 0; hcur[i] = 0; }
    __syncthreads();
    for (int i = t; i < m; i += 256)
        atomicAdd(&hcnt[ei[E + e0 + i] >> 8], 1);
    __syncthreads();
    for (int i = t; i < MAXB; i += 256) hoff[i] = hcnt[i];
    __syncthreads();
    exscan512(hoff, part, t);
    for (int i = t; i < B; i += 256) {
        histT[(size_t)i * nchunks + c]   = hcnt[i];
        sstartT[(size_t)i * nchunks + c] = e0 + hoff[i];
        if (hcnt[i] > 0) atomicAdd(&bucketTot[i], hcnt[i]);
    }
    __syncthreads();
    for (int i = t; i < m; i += 256) {
        int src = ei[e0 + i], dst = ei[E + e0 + i];
        int b = dst >> 8;
        int pos = e0 + hoff[b] + atomicAdd(&hcur[b], 1);
        sorted[pos] = make_uint2((unsigned)src, (unsigned)dst);
    }
}

// ---- K2: exclusive scan of bucket totals -> adj base per bucket ----
__global__ void k2_scanB(const int* __restrict__ bucketTot, int B,
                         int* __restrict__ bucketBase) {
    __shared__ int a[MAXB], part[256];
    int t = threadIdx.x;
    a[t]       = (t < B) ? bucketTot[t] : 0;
    a[t + 256] = (t + 256 < B) ? bucketTot[t + 256] : 0;
    __syncthreads();
    exscan512(a, part, t);
    if (t < B) bucketBase[t] = a[t];
    if (t + 256 < B) bucketBase[t + 256] = a[t + 256];
    if (t == 255) bucketBase[B] = part[255];
}

// slice-table setup shared by K3a/K3c: this sub-block's chunk range
#define SLICE_SETUP                                                             \
    int b = blockIdx.x, sub = blockIdx.y, t = threadIdx.x;                      \
    int cpg = (nchunks + SUBS - 1) / SUBS;                                      \
    int c0 = sub * cpg;                                                         \
    int c1 = c0 + cpg; if (c1 > nchunks) c1 = nchunks;                          \
    int nc = c1 - c0; if (nc < 0) nc = 0;                                       \
    if (t < nc) {                                                               \
        slen[t]   = histT[(size_t)b * nchunks + c0 + t];                        \
        sstart[t] = sstartT[(size_t)b * nchunks + c0 + t];                      \
    }                                                                           \
    __syncthreads();                                                            \
    if (t == 0) {                                                               \
        int run = 0;                                                            \
        for (int i2 = 0; i2 < nc; ++i2) { soff[i2] = run; run += slen[i2]; }    \
        soff[nc] = run;                                                         \
    }                                                                           \
    __syncthreads();                                                            \
    int T = soff[nc];

#define SLICE_EDGE(i)                                                           \
    int lo = 0, hi = nc - 1;                                                    \
    while (lo < hi) { int mid = (lo + hi + 1) >> 1;                             \
                      if (soff[mid] <= (i)) lo = mid; else hi = mid - 1; }      \
    uint2 e = sorted[sstart[lo] + ((i) - soff[lo])];

// ---- K3a: per-node degree (bucket-private LDS count, coalesced flush) ----
__global__ __launch_bounds__(256) void k3a_deg(const uint2* __restrict__ sorted,
                                               const int* __restrict__ histT,
                                               const int* __restrict__ sstartT,
                                               int* __restrict__ deg,
                                               int n, int nchunks) {
    __shared__ int slen[64], sstart[64], soff[65];
    __shared__ int ncnt[256];
    SLICE_SETUP
    ncnt[t] = 0;
    __syncthreads();
    int vb = b << 8;
    for (int i = t; i < T; i += 256) {
        SLICE_EDGE(i)
        atomicAdd(&ncnt[(int)e.y - vb], 1);
    }
    __syncthreads();
    int v = vb + t;
    if (v < n && ncnt[t] > 0) atomicAdd(&deg[v], ncnt[t]);
}

// ---- K3b: per-bucket scan -> offs, plus dinv and graph counts ----
__global__ __launch_bounds__(256) void k3b_offs(const int* __restrict__ deg,
                                                const int* __restrict__ bucketBase,
                                                const int* __restrict__ batch,
                                                int* __restrict__ offs,
                                                float* __restrict__ dinv,
                                                int* __restrict__ cnt, int n) {
    __shared__ int a[512], part[256];
    int b = blockIdx.x, t = threadIdx.x;
    int v = (b << 8) + t;
    int dg = (v < n) ? deg[v] : 0;
    a[t] = dg; a[t + 256] = 0;
    __syncthreads();
    exscan512(a, part, t);
    if (v < n) {
        offs[v] = bucketBase[b] + a[t];
        dinv[v] = rsqrtf((float)(dg + 1));     // +1 = self loop
        atomicAdd(&cnt[batch[v]], 1);
    }
}

// ---- K3c: scatter src into bucket-private adj region ----
__global__ __launch_bounds__(256) void k3c_scatter(const uint2* __restrict__ sorted,
                                                   const int* __restrict__ histT,
                                                   const int* __restrict__ sstartT,
                                                   const int* __restrict__ offs,
                                                   int* __restrict__ cursor,
                                                   int* __restrict__ adj, int nchunks) {
    __shared__ int slen[64], sstart[64], soff[65];
    SLICE_SETUP
    for (int i = t; i < T; i += 256) {
        SLICE_EDGE(i)
        int dst = (int)e.y;
        int pos = offs[dst] + atomicAdd(&cursor[dst], 1);
        adj[pos] = (int)e.x;
    }
}

// ---- prep: Wt[c][k] = f16(W1[k][c]) ----
__global__ void prep_wt(const float* __restrict__ W, __half* __restrict__ Wt) {
    int t = blockIdx.x * blockDim.x + threadIdx.x;
    int c = t & 127, k = t >> 7;
    Wt[c * 128 + k] = __float2half(W[(size_t)k * 128 + c]);
}

// ---- GEMM1 (MFMA f16): hs1 = (x @ W1) * dinv[row], f16 out ----
__global__ __launch_bounds__(256) void gemm1_mfma(const float* __restrict__ X,
                                                  const __half* __restrict__ Wt,
                                                  const float* __restrict__ dinv,
                                                  __half* __restrict__ out, int n) {
    __shared__ __align__(16) unsigned char As[64 * 128 * 2];
    __shared__ __align__(16) unsigned char Bs[128 * 128 * 2];
    int t = threadIdx.x;
    int wid = t >> 6, lane = t & 63;
    int qw = lane >> 4, lr = lane & 15;
    int rowBase = blockIdx.x * 64;

#pragma unroll
    for (int c = 0; c < 4; ++c) {
        int id = c * 256 + t;
        int r = id >> 4, kc = id & 15;
        int gr = rowBase + r;
        float4 x0, x1;
        if (gr < n) {
            const float4* src = (const float4*)(X + (size_t)gr * 128 + kc * 8);
            x0 = src[0]; x1 = src[1];
        } else {
            x0 = make_float4(0.f, 0.f, 0.f, 0.f); x1 = x0;
        }
        __half2 h0 = __floats2half2_rn(x0.x, x0.y);
        __half2 h1 = __floats2half2_rn(x0.z, x0.w);
        __half2 h2 = __floats2half2_rn(x1.x, x1.y);
        __half2 h3 = __floats2half2_rn(x1.z, x1.w);
        uint4 w;
        w.x = *(unsigned int*)&h0; w.y = *(unsigned int*)&h1;
        w.z = *(unsigned int*)&h2; w.w = *(unsigned int*)&h3;
        int byte = (r * 256 + kc * 16) ^ ((r & 7) << 4);
        *(uint4*)(As + byte) = w;
    }
#pragma unroll
    for (int c = 0; c < 8; ++c) {
        int id = c * 256 + t;
        int cr = id >> 4, kc = id & 15;
        uint4 w = *(const uint4*)(Wt + (size_t)cr * 128 + kc * 8);
        int byte = (cr * 256 + kc * 16) ^ ((cr & 7) << 4);
        *(uint4*)(Bs + byte) = w;
    }
    __syncthreads();

    floatx4 acc[4][2] = {};
#pragma unroll
    for (int ks = 0; ks < 4; ++ks) {
        int kb = ks * 32 + qw * 8;
        half8 a[4], b[2];
#pragma unroll
        for (int m = 0; m < 4; ++m) {
            int row = m * 16 + lr;
            int byte = (row * 256 + kb * 2) ^ ((row & 7) << 4);
            a[m] = *(const half8*)(As + byte);
        }
#pragma unroll
        for (int nn = 0; nn < 2; ++nn) {
            int col = wid * 32 + nn * 16 + lr;
            int byte = (col * 256 + kb * 2) ^ ((col & 7) << 4);
            b[nn] = *(const half8*)(Bs + byte);
        }
#pragma unroll
        for (int m = 0; m < 4; ++m)
#pragma unroll
            for (int nn = 0; nn < 2; ++nn)
                acc[m][nn] = __builtin_amdgcn_mfma_f32_16x16x32_f16(a[m], b[nn], acc[m][nn], 0, 0, 0);
    }

#pragma unroll
    for (int m = 0; m < 4; ++m) {
#pragma unroll
        for (int q = 0; q < 4; ++q) {
            int gr = rowBase + m * 16 + qw * 4 + q;
            if (gr < n) {
                float dv = dinv[gr];
#pragma unroll
                for (int nn = 0; nn < 2; ++nn) {
                    int col = wid * 32 + nn * 16 + lr;
                    out[(size_t)gr * 128 + col] = __float2half(acc[m][nn][q] * dv);
                }
            }
        }
    }
}

// lane holds features [2*lane, 2*lane+1]: one half2 (4B) per lane, 256B row.
__device__ __forceinline__ void acc_h2(unsigned int rv, float2& a) {
    float2 f = __half22float2(*(__half2*)&rv);
    a.x += f.x; a.y += f.y;
}
#define ROWP(buf, u) ((const unsigned int*)((buf) + (size_t)(u) * 128))

// Software-pipelined neighbor sum (r7 verified).
#define PIPE_GATHER(buf)                                                        \
    int nb = d >> 3;                                                            \
    int i = nb << 3;                                                            \
    if (nb > 0) {                                                               \
        int u0 = adj[start+0], u1 = adj[start+1], u2 = adj[start+2],            \
            u3 = adj[start+3], u4 = adj[start+4], u5 = adj[start+5],            \
            u6 = adj[start+6], u7 = adj[start+7];                               \
        unsigned c0 = ROWP(buf,u0)[lane], c1 = ROWP(buf,u1)[lane];              \
        unsigned c2 = ROWP(buf,u2)[lane], c3 = ROWP(buf,u3)[lane];              \
        unsigned c4 = ROWP(buf,u4)[lane], c5 = ROWP(buf,u5)[lane];              \
        unsigned c6 = ROWP(buf,u6)[lane], c7 = ROWP(buf,u7)[lane];              \
        for (int bq = 1; bq < nb; ++bq) {                                       \
            int bs = start + (bq << 3);                                         \
            int t0 = adj[bs+0], t1 = adj[bs+1], t2 = adj[bs+2], t3 = adj[bs+3]; \
            int t4 = adj[bs+4], t5 = adj[bs+5], t6 = adj[bs+6], t7 = adj[bs+7]; \
            unsigned n0 = ROWP(buf,t0)[lane], n1 = ROWP(buf,t1)[lane];          \
            unsigned n2 = ROWP(buf,t2)[lane], n3 = ROWP(buf,t3)[lane];          \
            unsigned n4 = ROWP(buf,t4)[lane], n5 = ROWP(buf,t5)[lane];          \
            unsigned n6 = ROWP(buf,t6)[lane], n7 = ROWP(buf,t7)[lane];          \
            acc_h2(c0, a0); acc_h2(c1, a1); acc_h2(c2, a2); acc_h2(c3, a3);     \
            acc_h2(c4, a0); acc_h2(c5, a1); acc_h2(c6, a2); acc_h2(c7, a3);     \
            c0 = n0; c1 = n1; c2 = n2; c3 = n3;                                 \
            c4 = n4; c5 = n5; c6 = n6; c7 = n7;                                 \
        }                                                                       \
        acc_h2(c0, a0); acc_h2(c1, a1); acc_h2(c2, a2); acc_h2(c3, a3);         \
        acc_h2(c4, a0); acc_h2(c5, a1); acc_h2(c6, a2); acc_h2(c7, a3);         \
    }                                                                           \
    for (; i + 3 < d; i += 4) {                                                 \
        int u0 = adj[start+i+0], u1 = adj[start+i+1];                           \
        int u2 = adj[start+i+2], u3 = adj[start+i+3];                           \
        unsigned r0 = ROWP(buf,u0)[lane], r1 = ROWP(buf,u1)[lane];              \
        unsigned r2 = ROWP(buf,u2)[lane], r3 = ROWP(buf,u3)[lane];              \
        acc_h2(r0, a0); acc_h2(r1, a1); acc_h2(r2, a2); acc_h2(r3, a3);         \
    }                                                                           \
    for (; i < d; ++i) acc_h2(ROWP(buf, adj[start + i])[lane], a0);

// ---- gather1: g1 = relu(dinv*(self+neighbors)+b1); store gs1 = g1*dinv ----
__global__ void gather1(const __half* __restrict__ hs, const int* __restrict__ adj,
                        const int* __restrict__ offs, const int* __restrict__ deg,
                        const float* __restrict__ dinv, const float* __restrict__ b1,
                        __half* __restrict__ gs, int n) {
    int wave = threadIdx.x >> 6;
    int lane = threadIdx.x & 63;
    int v = blockIdx.x * 4 + wave;
    if (v >= n) return;
    float2 a0 = make_float2(0.f, 0.f), a1 = a0, a2 = a0, a3 = a0;
    acc_h2(ROWP(hs, v)[lane], a0);                   // self loop
    int start = __builtin_amdgcn_readfirstlane(offs[v]);
    int d     = __builtin_amdgcn_readfirstlane(deg[v]);
    PIPE_GATHER(hs)
    float accx = (a0.x + a1.x) + (a2.x + a3.x);
    float accy = (a0.y + a1.y) + (a2.y + a3.y);
    float dv = dinv[v];
    float2 bb = ((const float2*)b1)[lane];
    float g0 = fmaxf(accx * dv + bb.x, 0.f) * dv;
    float g1 = fmaxf(accy * dv + bb.y, 0.f) * dv;
    __half2 h = __floats2half2_rn(g0, g1);
    ((unsigned int*)(gs + (size_t)v * 128))[lane] = *(unsigned int*)&h;
}

// ---- gather2 + LDS-pooled mean-pool accumulate ----
__global__ void gather2_pool(const __half* __restrict__ gs, const int* __restrict__ adj,
                             const int* __restrict__ offs, const int* __restrict__ deg,
                             const float* __restrict__ dinv, const int* __restrict__ batch,
                             float* __restrict__ poolsum, int n) {
    __shared__ float poolacc[128];
    int t = threadIdx.x;
    int wave = t >> 6;
    int lane = t & 63;
    if (t < 128) poolacc[t] = 0.f;
    int gref = batch[blockIdx.x * 4];                // first node always < n
    __syncthreads();
    int v = blockIdx.x * 4 + wave;
    if (v < n) {
        float2 a0 = make_float2(0.f, 0.f), a1 = a0, a2 = a0, a3 = a0;
        acc_h2(ROWP(gs, v)[lane], a0);
        int start = __builtin_amdgcn_readfirstlane(offs[v]);
        int d     = __builtin_amdgcn_readfirstlane(deg[v]);
        PIPE_GATHER(gs)
        float accx = (a0.x + a1.x) + (a2.x + a3.x);
        float accy = (a0.y + a1.y) + (a2.y + a3.y);
        float dv = dinv[v];
        int g = batch[v];
        if (g == gref) {                             // common case: LDS atomic
            atomicAdd(&poolacc[lane * 2 + 0], accx * dv);
            atomicAdd(&poolacc[lane * 2 + 1], accy * dv);
        } else {                                     // graph boundary: direct
            float* p = poolsum + (size_t)g * 128;
            atomicAdd(&p[lane * 2 + 0], accx * dv);
            atomicAdd(&p[lane * 2 + 1], accy * dv);
        }
    }
    __syncthreads();
    if (t < 128) {
        float s = poolacc[t];
        if (s != 0.f) atomicAdd(&poolsum[(size_t)gref * 128 + t], s);
    }
}

// ---- head: emb = (pool/cnt) @ W2 + b2 ; logits = emb @ Wg + bg ----
__global__ void head(const float* __restrict__ poolsum, const int* __restrict__ cnt,
                     const float* __restrict__ W2, const float* __restrict__ b2,
                     const float* __restrict__ Wg, const float* __restrict__ bg,
                     float* __restrict__ out, int G) {
    __shared__ float pm[128];
    __shared__ float emb[256];
    int g = blockIdx.x, t = threadIdx.x;
    float inv = 1.f / fmaxf((float)cnt[g], 1.f);
    if (t < 128) pm[t] = poolsum[(size_t)g * 128 + t] * inv;
    __syncthreads();
    float acc = b2[t];
    for (int k = 0; k < 128; ++k) acc += pm[k] * W2[k * 256 + t];
    out[(size_t)g * 256 + t] = acc;
    emb[t] = acc;
    __syncthreads();
    if (t < 16) {
        float a = bg[t];
        for (int j = 0; j < 256; ++j) a += emb[j] * Wg[j * 16 + t];
        out[(size_t)G * 256 + g * 16 + t] = a;
    }
}

extern "C" void kernel_launch(void* const* d_in, const int* in_sizes, int n_in,
                              void* d_out, int out_size, void* d_ws, size_t ws_size,
                              hipStream_t stream) {
    const float* x     = (const float*)d_in[0];
    const int*   ei    = (const int*)d_in[1];
    const int*   batch = (const int*)d_in[2];
    const float* W1    = (const float*)d_in[4];
    const float* b1    = (const float*)d_in[5];
    const float* W2    = (const float*)d_in[6];
    const float* b2    = (const float*)d_in[7];
    const float* Wg    = (const float*)d_in[8];
    const float* bg    = (const float*)d_in[9];
    float* out = (float*)d_out;

    int n = in_sizes[0] / 128;
    int E = in_sizes[1] / 2;
    int G = out_size / (256 + 16);
    int B = (n + 255) >> 8;                 // buckets of 256 nodes (<= 512)
    int nchunks = (E + CHUNK - 1) / CHUNK;  // <= 512

    char* ws = (char*)d_ws;
    auto alloc = [&](size_t bytes) {
        char* p = ws;
        ws += (bytes + 255) & ~(size_t)255;
        return p;
    };
    int*    deg       = (int*)alloc((size_t)n * 4);
    float*  dinv      = (float*)alloc((size_t)n * 4);
    int*    offs      = (int*)alloc((size_t)n * 4);
    int*    cursor    = (int*)alloc((size_t)n * 4);
    int*    adj       = (int*)alloc((size_t)E * 4);
    uint2*  sorted    = (uint2*)alloc((size_t)E * 8);
    int*    histT     = (int*)alloc((size_t)B * nchunks * 4);
    int*    sstartT   = (int*)alloc((size_t)B * nchunks * 4);
    int*    bucketTot = (int*)alloc((size_t)(B + 1) * 4);
    int*    bucketBase= (int*)alloc((size_t)(B + 1) * 4);
    int*    cnt       = (int*)alloc((size_t)G * 4);
    float*  poolsum   = (float*)alloc((size_t)G * 128 * 4);
    __half* Wt        = (__half*)alloc(128 * 128 * 2);
    __half* hs1       = (__half*)alloc((size_t)n * 128 * 2);
    __half* gs1       = (__half*)alloc((size_t)n * 128 * 2);

    hipMemsetAsync(deg, 0, (size_t)n * 4, stream);
    hipMemsetAsync(cursor, 0, (size_t)n * 4, stream);
    hipMemsetAsync(bucketTot, 0, (size_t)(B + 1) * 4, stream);
    hipMemsetAsync(cnt, 0, (size_t)G * 4, stream);
    hipMemsetAsync(poolsum, 0, (size_t)G * 128 * 4, stream);

    k1_bucket<<<nchunks, 256, 0, stream>>>(ei, E, B, nchunks, sorted, histT, sstartT, bucketTot);
    k2_scanB<<<1, 256, 0, stream>>>(bucketTot, B, bucketBase);
    k3a_deg<<<dim3(B, SUBS), 256, 0, stream>>>(sorted, histT, sstartT, deg, n, nchunks);
    k3b_offs<<<B, 256, 0, stream>>>(deg, bucketBase, batch, offs, dinv, cnt, n);
    k3c_scatter<<<dim3(B, SUBS), 256, 0, stream>>>(sorted, histT, sstartT, offs, cursor, adj, nchunks);

    prep_wt<<<64, TPB, 0, stream>>>(W1, Wt);
    gemm1_mfma<<<(n + 63) / 64, 256, 0, stream>>>(x, Wt, dinv, hs1, n);
    gather1<<<(n + 3) / 4, 256, 0, stream>>>(hs1, adj, offs, deg, dinv, b1, gs1, n);
    gather2_pool<<<(n + 3) / 4, 256, 0, stream>>>(gs1, adj, offs, deg, dinv, batch, poolsum, n);
    head<<<G, 256, 0, stream>>>(poolsum, cnt, W2, b2, Wg, bg, out, G);
}